// Round 1
// baseline (645.978 us; speedup 1.0000x reference)
//
#include <hip/hip_runtime.h>
#include <stdint.h>

#define BM 128
#define BN 128
#define BK 32

typedef __attribute__((ext_vector_type(8))) short short8_t;
typedef __attribute__((ext_vector_type(4))) short short4v;
typedef __attribute__((ext_vector_type(4))) float floatx4;

static __device__ __forceinline__ unsigned short f2bf(float f) {
    union { float f; unsigned u; } c; c.f = f;
    unsigned r = c.u + 0x7fffu + ((c.u >> 16) & 1u);
    return (unsigned short)(r >> 16);
}
static __device__ __forceinline__ float bf2f(unsigned short h) {
    union { unsigned u; float f; } c; c.u = ((unsigned)h) << 16;
    return c.f;
}

static __device__ __forceinline__ void async_load16(const void* g, void* l) {
    __builtin_amdgcn_global_load_lds(
        (const __attribute__((address_space(1))) unsigned int*)g,
        (__attribute__((address_space(3))) unsigned int*)l, 16, 0, 0);
}

// Stage a 128x32 bf16 tile from global (row-major, ld elements) into LDS
// laid out as [4 kblk][128 m][8 k] shorts. Chunk c (16B) <-> (kblk=c>>7, m=c&127).
static __device__ __forceinline__ void stage_bf16(const short* src, int ld, short* lds, int tid) {
    int lane = tid & 63;
    int base = (tid >> 6) * 64;
#pragma unroll
    for (int t = 0; t < 2; ++t) {
        int c = base + t * 256 + lane;
        int m = c & 127, kb = c >> 7;
        const short* gp = src + (size_t)m * ld + kb * 8;
        short* lp = lds + (size_t)(base + t * 256) * 8;  // wave-uniform; HW adds lane*16B
        async_load16(gp, lp);
    }
}

// Stage a 128x32 fp32 tile, splitting into hi(/lo) bf16 LDS tiles ([4][128][8]).
template <bool DO_LO>
static __device__ __forceinline__ void stage_f32(const float* src, int ld, short* ldsH,
                                                 short* ldsL, int tid) {
#pragma unroll
    for (int t = 0; t < 4; ++t) {
        int c = tid + t * 256;          // 16B fp32 chunk id, 0..1023
        int r = c >> 3, cf = c & 7;     // row, 4-float group
        float4 x = *(const float4*)(src + (size_t)r * ld + cf * 4);
        float xs[4] = {x.x, x.y, x.z, x.w};
        short4v hv, lv;
#pragma unroll
        for (int i = 0; i < 4; ++i) {
            unsigned short h = f2bf(xs[i]);
            hv[i] = (short)h;
            if (DO_LO) lv[i] = (short)f2bf(xs[i] - bf2f(h));
        }
        int off = (((c >> 1) & 3) * 128 + r) * 8 + (c & 1) * 4;
        *(short4v*)(ldsH + off) = hv;
        if (DO_LO) *(short4v*)(ldsL + off) = lv;
    }
}

static __device__ __forceinline__ short8_t frag(const short* lds, int row, int quad) {
    return *(const short8_t*)(lds + ((quad << 7) + row) * 8);
}

// AMODE: 0=A bf16 single, 1=A bf16 dual(hi/lo), 2=A fp32 split-on-the-fly, 3=A fp32 hi-only
// BMODE: 0=B bf16 single, 1=B bf16 dual        (B inputs are pre-transposed [N][K])
// CMODE: 0=fp32 out(+bias), 1=bf16 out, 2=bf16 hi/lo pair out(+bias), 3=bf16 transposed vT out(+bias)
template <int AMODE, int BMODE, int CMODE>
__global__ __launch_bounds__(256, 2) void gemm_k(
    const void* Ap0, const void* Ap1, int lda, long long a_zoff,
    const short* Bp0, const short* Bp1, int ldb, long long b_zoff,
    void* Cp0, void* Cp1, int ldc, long long c_zoff,
    const float* bias, int K)
{
    constexpr bool ASPLIT = (AMODE == 1 || AMODE == 2);
    constexpr bool BSPLIT = (BMODE == 1);
    constexpr bool TRIPLE = ASPLIT && BSPLIT;

    __shared__ __align__(16) short Ah[4 * 128 * 8];
    __shared__ __align__(16) short Bh[4 * 128 * 8];
    __shared__ __align__(16) short Al[ASPLIT ? 4 * 128 * 8 : 8];
    __shared__ __align__(16) short Bl[BSPLIT ? 4 * 128 * 8 : 8];

    int tid = threadIdx.x;
    int lane = tid & 63;
    int wid = tid >> 6;
    int wm = wid >> 1, wn = wid & 1;
    int z = blockIdx.z;
    size_t row0 = (size_t)blockIdx.y * BM;
    size_t col0 = (size_t)blockIdx.x * BN;

    floatx4 acc[4][4];
#pragma unroll
    for (int i = 0; i < 4; ++i)
#pragma unroll
        for (int j = 0; j < 4; ++j) acc[i][j] = floatx4{0.f, 0.f, 0.f, 0.f};

    const short* b0 = Bp0 + (size_t)z * b_zoff + col0 * ldb;
    const short* b1 = nullptr;
    if constexpr (BSPLIT) b1 = Bp1 + (size_t)z * b_zoff + col0 * ldb;

    const short* a0s = nullptr;
    const short* a1s = nullptr;
    const float* a0f = nullptr;
    if constexpr (AMODE == 2 || AMODE == 3) {
        a0f = (const float*)Ap0 + (size_t)z * a_zoff + row0 * lda;
    } else {
        a0s = (const short*)Ap0 + (size_t)z * a_zoff + row0 * lda;
        if constexpr (AMODE == 1) a1s = (const short*)Ap1 + (size_t)z * a_zoff + row0 * lda;
    }

    int quad = lane >> 4, mr = lane & 15;

    for (int k0 = 0; k0 < K; k0 += BK) {
        __syncthreads();
        if constexpr (AMODE == 0) {
            stage_bf16(a0s + k0, lda, Ah, tid);
        } else if constexpr (AMODE == 1) {
            stage_bf16(a0s + k0, lda, Ah, tid);
            stage_bf16(a1s + k0, lda, Al, tid);
        } else if constexpr (AMODE == 2) {
            stage_f32<true>(a0f + k0, lda, Ah, Al, tid);
        } else {
            stage_f32<false>(a0f + k0, lda, Ah, nullptr, tid);
        }
        stage_bf16(b0 + k0, ldb, Bh, tid);
        if constexpr (BSPLIT) stage_bf16(b1 + k0, ldb, Bl, tid);
        __syncthreads();

        short8_t ah[4], al[4];
#pragma unroll
        for (int i = 0; i < 4; ++i) {
            ah[i] = frag(Ah, wm * 64 + i * 16 + mr, quad);
            if constexpr (TRIPLE) al[i] = frag(Al, wm * 64 + i * 16 + mr, quad);
        }
#pragma unroll
        for (int j = 0; j < 4; ++j) {
            short8_t bh = frag(Bh, wn * 64 + j * 16 + mr, quad);
            short8_t bl;
            if constexpr (TRIPLE) bl = frag(Bl, wn * 64 + j * 16 + mr, quad);
#pragma unroll
            for (int i = 0; i < 4; ++i) {
                acc[i][j] = __builtin_amdgcn_mfma_f32_16x16x32_bf16(ah[i], bh, acc[i][j], 0, 0, 0);
                if constexpr (TRIPLE) {
                    acc[i][j] = __builtin_amdgcn_mfma_f32_16x16x32_bf16(ah[i], bl, acc[i][j], 0, 0, 0);
                    acc[i][j] = __builtin_amdgcn_mfma_f32_16x16x32_bf16(al[i], bh, acc[i][j], 0, 0, 0);
                }
            }
        }
    }

#pragma unroll
    for (int i = 0; i < 4; ++i) {
#pragma unroll
        for (int j = 0; j < 4; ++j) {
#pragma unroll
            for (int r = 0; r < 4; ++r) {
                size_t rr = row0 + (size_t)(wm * 64 + i * 16 + quad * 4 + r);
                size_t cc = col0 + (size_t)(wn * 64 + j * 16 + mr);
                float v = acc[i][j][r];
                if (bias) v += bias[cc];
                if constexpr (CMODE == 0) {
                    float* C = (float*)Cp0 + (size_t)z * c_zoff;
                    C[rr * ldc + cc] = v;
                } else if constexpr (CMODE == 1) {
                    unsigned short* C = (unsigned short*)Cp0 + (size_t)z * c_zoff;
                    C[rr * ldc + cc] = f2bf(v);
                } else if constexpr (CMODE == 2) {
                    unsigned short* C0 = (unsigned short*)Cp0;
                    unsigned short* C1 = (unsigned short*)Cp1;
                    unsigned short h = f2bf(v);
                    C0[rr * ldc + cc] = h;
                    C1[rr * ldc + cc] = f2bf(v - bf2f(h));
                } else {  // vT[b][col][s], b = rr>>11, s = rr&2047, col dim 1024, s dim 2048
                    unsigned short* C = (unsigned short*)Cp0;
                    size_t b = rr >> 11, s = rr & 2047;
                    C[((b << 10) + cc) * 2048 + s] = f2bf(v);
                }
            }
        }
    }
}

template <bool DO_LO>
__global__ __launch_bounds__(256) void transpose_split_k(const float* W, unsigned short* Th,
                                                         unsigned short* Tl, int n) {
    __shared__ float tile[32][33];
    int bx = blockIdx.x * 32;  // input col / output row base
    int by = blockIdx.y * 32;  // input row base
    int tx = threadIdx.x & 31;
    int ty = threadIdx.x >> 5;  // 0..7
    for (int r = ty; r < 32; r += 8) tile[r][tx] = W[(size_t)(by + r) * n + bx + tx];
    __syncthreads();
    for (int r = ty; r < 32; r += 8) {
        float v = tile[tx][r];  // = W[by+tx][bx+r]
        unsigned short h = f2bf(v);
        Th[(size_t)(bx + r) * n + by + tx] = h;
        if (DO_LO) Tl[(size_t)(bx + r) * n + by + tx] = f2bf(v - bf2f(h));
    }
}

// One block per row of 2048 fp32 logits; writes bf16 attn into the first half
// of the same row's storage (row byte stride stays 8192 => bf16 lda 4096).
__global__ __launch_bounds__(256) void softmax_k(float* scores) {
    size_t row = blockIdx.x;
    float* rp = scores + row * 2048;
    int tid = threadIdx.x;
    int lane = tid & 63, w = tid >> 6;
    float x[8];
    float mx = -3.4e38f;
#pragma unroll
    for (int i = 0; i < 8; ++i) {
        x[i] = rp[tid + i * 256];
        mx = fmaxf(mx, x[i]);
    }
#pragma unroll
    for (int o = 32; o > 0; o >>= 1) mx = fmaxf(mx, __shfl_xor(mx, o, 64));
    __shared__ float redm[4];
    __shared__ float reds[4];
    if (lane == 0) redm[w] = mx;
    __syncthreads();  // also orders: all row reads complete before any write below
    mx = fmaxf(fmaxf(redm[0], redm[1]), fmaxf(redm[2], redm[3]));
    float s = 0.f;
#pragma unroll
    for (int i = 0; i < 8; ++i) {
        x[i] = __expf(x[i] - mx);
        s += x[i];
    }
#pragma unroll
    for (int o = 32; o > 0; o >>= 1) s += __shfl_xor(s, o, 64);
    if (lane == 0) reds[w] = s;
    __syncthreads();
    s = reds[0] + reds[1] + reds[2] + reds[3];
    float inv = 1.f / s;
    unsigned short* op = (unsigned short*)rp;
#pragma unroll
    for (int i = 0; i < 8; ++i) op[tid + i * 256] = f2bf(x[i] * inv);
}

extern "C" void kernel_launch(void* const* d_in, const int* in_sizes, int n_in,
                              void* d_out, int out_size, void* d_ws, size_t ws_size,
                              hipStream_t stream) {
    const float* query  = (const float*)d_in[0];
    const float* keys   = (const float*)d_in[1];
    const float* values = (const float*)d_in[2];
    const float* Wq = (const float*)d_in[3];
    const float* bq = (const float*)d_in[4];
    const float* Wk = (const float*)d_in[5];
    const float* bk = (const float*)d_in[6];
    const float* Wv = (const float*)d_in[7];
    const float* bv = (const float*)d_in[8];
    const float* Wd = (const float*)d_in[9];
    const float* bd = (const float*)d_in[10];
    float* out = (float*)d_out;

    const int S = 2048, D = 1024, NB = 4;
    const size_t TEN = (size_t)NB * S * D;  // 8.39M elements

    char* p = (char*)d_ws;
    auto alloc = [&](size_t bytes) {
        char* r = p;
        p += (bytes + 255) & ~(size_t)255;
        return r;
    };
    short* q_h = (short*)alloc(TEN * 2);
    short* q_l = (short*)alloc(TEN * 2);
    short* k_h = (short*)alloc(TEN * 2);
    short* k_l = (short*)alloc(TEN * 2);
    short* vT  = (short*)alloc(TEN * 2);
    unsigned short* WqTh = (unsigned short*)alloc((size_t)D * D * 2);
    unsigned short* WqTl = (unsigned short*)alloc((size_t)D * D * 2);
    unsigned short* WkTh = (unsigned short*)alloc((size_t)D * D * 2);
    unsigned short* WkTl = (unsigned short*)alloc((size_t)D * D * 2);
    unsigned short* WvT  = (unsigned short*)alloc((size_t)D * D * 2);
    unsigned short* WdT  = (unsigned short*)alloc((size_t)D * D * 2);
    float* scores = (float*)p;
    long long avail = (long long)ws_size - (long long)(p - (char*)d_ws);
    long long sbytes = (long long)S * S * 4;
    int g = (avail >= 4 * sbytes) ? 4 : (avail >= 2 * sbytes) ? 2 : 1;
    short* att = q_h;  // alias: q_h rows of batch b are dead once batch b's scores are done

    dim3 blk(256);
    dim3 tgrid(D / 32, D / 32);
    transpose_split_k<true><<<tgrid, blk, 0, stream>>>(Wq, WqTh, WqTl, D);
    transpose_split_k<true><<<tgrid, blk, 0, stream>>>(Wk, WkTh, WkTl, D);
    transpose_split_k<false><<<tgrid, blk, 0, stream>>>(Wv, WvT, nullptr, D);
    transpose_split_k<false><<<tgrid, blk, 0, stream>>>(Wd, WdT, nullptr, D);

    dim3 pgrid(D / BN, (NB * S) / BM, 1);  // (8, 64)
    // q/k projections: fp32 A split on the fly, split-transposed W, hi/lo bf16 outputs
    gemm_k<2, 1, 2><<<pgrid, blk, 0, stream>>>(query, nullptr, D, 0,
        (const short*)WqTh, (const short*)WqTl, D, 0,
        q_h, q_l, D, 0, bq, D);
    gemm_k<2, 1, 2><<<pgrid, blk, 0, stream>>>(keys, nullptr, D, 0,
        (const short*)WkTh, (const short*)WkTl, D, 0,
        k_h, k_l, D, 0, bk, D);
    // v projection: plain bf16, epilogue writes transposed vT[b][h][s]
    gemm_k<3, 0, 3><<<pgrid, blk, 0, stream>>>(values, nullptr, D, 0,
        (const short*)WvT, nullptr, D, 0,
        vT, nullptr, 0, 0, bv, D);

    for (int g0 = 0; g0 < NB; g0 += g) {
        int gz = (NB - g0 < g) ? (NB - g0) : g;
        // scores = q kT (split 3-term), fp32 out
        dim3 sgrid(S / BN, S / BM, gz);  // (16,16,gz)
        gemm_k<1, 1, 0><<<sgrid, blk, 0, stream>>>(
            q_h + (size_t)g0 * S * D, q_l + (size_t)g0 * S * D, D, (long long)S * D,
            k_h + (size_t)g0 * S * D, k_l + (size_t)g0 * S * D, D, (long long)S * D,
            scores, nullptr, S, (long long)S * S, nullptr, D);
        softmax_k<<<dim3((unsigned)(gz * S)), blk, 0, stream>>>(scores);
        // attended = attn @ v : A = bf16 attn (row stride 4096 shorts), B = vT
        dim3 agrid(D / BN, S / BM, gz);  // (8,16,gz)
        gemm_k<0, 0, 1><<<agrid, blk, 0, stream>>>(
            (const short*)scores, nullptr, 2 * S, (long long)S * 2 * S,
            vT + (size_t)g0 * D * S, nullptr, S, (long long)D * S,
            att + (size_t)g0 * S * D, nullptr, D, (long long)S * D, nullptr, S);
    }

    // out = attended @ Wd + bd, fp32
    gemm_k<0, 0, 0><<<pgrid, blk, 0, stream>>>(
        (const short*)att, nullptr, D, 0,
        (const short*)WdT, nullptr, D, 0,
        out, nullptr, D, 0, bd, D);
}

// Round 2
// 535.078 us; speedup vs baseline: 1.2073x; 1.2073x over previous
//
#include <hip/hip_runtime.h>
#include <stdint.h>

#define BM 128
#define BN 128
#define BK 32

typedef _Float16 f16;
typedef __attribute__((ext_vector_type(8))) _Float16 f16x8;
typedef __attribute__((ext_vector_type(4))) _Float16 f16x4;
typedef __attribute__((ext_vector_type(4))) float floatx4;

static __device__ __forceinline__ void async_load16(const void* g, void* l) {
    __builtin_amdgcn_global_load_lds(
        (const __attribute__((address_space(1))) unsigned int*)g,
        (__attribute__((address_space(3))) unsigned int*)l, 16, 0, 0);
}

// Stage a 128x32 f16 tile from global (row-major, ld elements) into LDS
// laid out as [4 kblk][128 m][8 k]. Chunk c (16B) <-> (kblk=c>>7, m=c&127).
static __device__ __forceinline__ void stage_tile(const f16* src, int ld, f16* lds, int tid) {
    int lane = tid & 63;
    int base = (tid >> 6) * 64;
#pragma unroll
    for (int t = 0; t < 2; ++t) {
        int c = base + t * 256 + lane;
        int m = c & 127, kb = c >> 7;
        const f16* gp = src + (size_t)m * ld + kb * 8;
        f16* lp = lds + (size_t)(base + t * 256) * 8;  // wave-uniform; HW adds lane*16B
        async_load16(gp, lp);
    }
}

static __device__ __forceinline__ f16x8 frag(const f16* lds, int row, int quad) {
    return *(const f16x8*)(lds + ((quad << 7) + row) * 8);
}

// CMODE: 0 = fp32 out (+bias), 1 = f16 out (+bias), 3 = f16 transposed vT out (+bias)
template <int CMODE>
static __device__ __forceinline__ void gemm_body(
    const f16* Ap, int lda, long long a_zoff,
    const f16* Bp, int ldb, long long b_zoff,
    void* Cp, int ldc, long long c_zoff,
    const float* bias, int K)
{
    __shared__ __align__(16) f16 As[4 * 128 * 8];
    __shared__ __align__(16) f16 Bs[4 * 128 * 8];

    int tid = threadIdx.x;
    int lane = tid & 63;
    int wid = tid >> 6;
    int wm = wid >> 1, wn = wid & 1;
    int z = blockIdx.z;
    size_t row0 = (size_t)blockIdx.y * BM;
    size_t col0 = (size_t)blockIdx.x * BN;

    floatx4 acc[4][4];
#pragma unroll
    for (int i = 0; i < 4; ++i)
#pragma unroll
        for (int j = 0; j < 4; ++j) acc[i][j] = floatx4{0.f, 0.f, 0.f, 0.f};

    const f16* a0 = Ap + (size_t)z * a_zoff + row0 * lda;
    const f16* b0 = Bp + (size_t)z * b_zoff + col0 * ldb;

    int quad = lane >> 4, mr = lane & 15;

    for (int k0 = 0; k0 < K; k0 += BK) {
        __syncthreads();
        stage_tile(a0 + k0, lda, As, tid);
        stage_tile(b0 + k0, ldb, Bs, tid);
        __syncthreads();

        f16x8 ah[4];
#pragma unroll
        for (int i = 0; i < 4; ++i) ah[i] = frag(As, wm * 64 + i * 16 + mr, quad);
#pragma unroll
        for (int j = 0; j < 4; ++j) {
            f16x8 bh = frag(Bs, wn * 64 + j * 16 + mr, quad);
#pragma unroll
            for (int i = 0; i < 4; ++i)
                acc[i][j] = __builtin_amdgcn_mfma_f32_16x16x32_f16(ah[i], bh, acc[i][j], 0, 0, 0);
        }
    }

#pragma unroll
    for (int i = 0; i < 4; ++i) {
#pragma unroll
        for (int j = 0; j < 4; ++j) {
#pragma unroll
            for (int r = 0; r < 4; ++r) {
                size_t rr = row0 + (size_t)(wm * 64 + i * 16 + quad * 4 + r);
                size_t cc = col0 + (size_t)(wn * 64 + j * 16 + mr);
                float v = acc[i][j][r];
                if (bias) v += bias[cc];
                if constexpr (CMODE == 0) {
                    float* C = (float*)Cp + (size_t)z * c_zoff;
                    C[rr * ldc + cc] = v;
                } else if constexpr (CMODE == 1) {
                    f16* C = (f16*)Cp + (size_t)z * c_zoff;
                    C[rr * ldc + cc] = (f16)v;
                } else {  // vT[b][col][s]: b = rr>>11, s = rr&2047, col dim 1024
                    f16* C = (f16*)Cp;
                    size_t b = rr >> 11, s = rr & 2047;
                    C[((b << 10) + cc) * 2048 + s] = (f16)v;
                }
            }
        }
    }
}

// Distinct symbols per pipeline stage so rocprof separates them.
__global__ __launch_bounds__(256, 2) void g_proj(const f16* A, int lda, const f16* B, int ldb,
                                                 f16* C, int ldc, const float* bias, int K) {
    gemm_body<1>(A, lda, 0, B, ldb, 0, C, ldc, 0, bias, K);
}
__global__ __launch_bounds__(256, 2) void g_projT(const f16* A, int lda, const f16* B, int ldb,
                                                  f16* C, const float* bias, int K) {
    gemm_body<3>(A, lda, 0, B, ldb, 0, C, 0, 0, bias, K);
}
__global__ __launch_bounds__(256, 2) void g_scores(const f16* A, int lda, long long az,
                                                   const f16* B, int ldb, long long bz,
                                                   float* C, int ldc, long long cz, int K) {
    gemm_body<0>(A, lda, az, B, ldb, bz, C, ldc, cz, nullptr, K);
}
__global__ __launch_bounds__(256, 2) void g_attnv(const f16* A, int lda, long long az,
                                                  const f16* B, int ldb, long long bz,
                                                  f16* C, int ldc, long long cz, int K) {
    gemm_body<1>(A, lda, az, B, ldb, bz, C, ldc, cz, nullptr, K);
}
__global__ __launch_bounds__(256, 2) void g_out(const f16* A, int lda, const f16* B, int ldb,
                                                float* C, int ldc, const float* bias, int K) {
    gemm_body<0>(A, lda, 0, B, ldb, 0, C, ldc, 0, bias, K);
}

// fp32 -> fp16 elementwise convert, 4 elements/thread.
__global__ __launch_bounds__(256) void cvt_f16(const float* src, f16* dst) {
    size_t i = ((size_t)blockIdx.x * 256 + threadIdx.x) * 4;
    float4 x = *(const float4*)(src + i);
    f16x4 h = {(f16)x.x, (f16)x.y, (f16)x.z, (f16)x.w};
    *(f16x4*)(dst + i) = h;
}

// W [n][n] fp32 -> W^T [n][n] fp16
__global__ __launch_bounds__(256) void wtrans(const float* W, f16* T, int n) {
    __shared__ float tile[32][33];
    int bx = blockIdx.x * 32;
    int by = blockIdx.y * 32;
    int tx = threadIdx.x & 31;
    int ty = threadIdx.x >> 5;
    for (int r = ty; r < 32; r += 8) tile[r][tx] = W[(size_t)(by + r) * n + bx + tx];
    __syncthreads();
    for (int r = ty; r < 32; r += 8) T[(size_t)(bx + r) * n + by + tx] = (f16)tile[tx][r];
}

// One block per row of 2048 fp32 logits; writes fp16 attn into the first half
// of the same row's storage (row byte stride stays 8192 => f16 lda 4096).
__global__ __launch_bounds__(256) void softmax_k(float* scores) {
    size_t row = blockIdx.x;
    float* rp = scores + row * 2048;
    int tid = threadIdx.x;
    int lane = tid & 63, w = tid >> 6;
    float x[8];
    float mx = -3.4e38f;
#pragma unroll
    for (int i = 0; i < 8; ++i) {
        x[i] = rp[tid + i * 256];
        mx = fmaxf(mx, x[i]);
    }
#pragma unroll
    for (int o = 32; o > 0; o >>= 1) mx = fmaxf(mx, __shfl_xor(mx, o, 64));
    __shared__ float redm[4];
    __shared__ float reds[4];
    if (lane == 0) redm[w] = mx;
    __syncthreads();  // also orders: all row reads complete before any write below
    mx = fmaxf(fmaxf(redm[0], redm[1]), fmaxf(redm[2], redm[3]));
    float s = 0.f;
#pragma unroll
    for (int i = 0; i < 8; ++i) {
        x[i] = __expf(x[i] - mx);
        s += x[i];
    }
#pragma unroll
    for (int o = 32; o > 0; o >>= 1) s += __shfl_xor(s, o, 64);
    if (lane == 0) reds[w] = s;
    __syncthreads();
    s = reds[0] + reds[1] + reds[2] + reds[3];
    float inv = 1.f / s;
    f16* op = (f16*)rp;
#pragma unroll
    for (int i = 0; i < 8; ++i) op[tid + i * 256] = (f16)(x[i] * inv);
}

extern "C" void kernel_launch(void* const* d_in, const int* in_sizes, int n_in,
                              void* d_out, int out_size, void* d_ws, size_t ws_size,
                              hipStream_t stream) {
    const float* query  = (const float*)d_in[0];
    const float* keys   = (const float*)d_in[1];
    const float* values = (const float*)d_in[2];
    const float* Wq = (const float*)d_in[3];
    const float* bq = (const float*)d_in[4];
    const float* Wk = (const float*)d_in[5];
    const float* bk = (const float*)d_in[6];
    const float* Wv = (const float*)d_in[7];
    const float* bv = (const float*)d_in[8];
    const float* Wd = (const float*)d_in[9];
    const float* bd = (const float*)d_in[10];
    float* out = (float*)d_out;

    const int S = 2048, D = 1024, NB = 4;
    const size_t TEN = (size_t)NB * S * D;  // 8.39M

    char* p = (char*)d_ws;
    auto alloc = [&](size_t bytes) {
        char* r = p;
        p += (bytes + 255) & ~(size_t)255;
        return r;
    };
    f16* xq = (f16*)alloc(TEN * 2);
    f16* xk = (f16*)alloc(TEN * 2);
    f16* xv = (f16*)alloc(TEN * 2);
    f16* q16 = (f16*)alloc(TEN * 2);
    f16* k16 = (f16*)alloc(TEN * 2);
    f16* vT  = (f16*)alloc(TEN * 2);
    f16* WqT = (f16*)alloc((size_t)D * D * 2);
    f16* WkT = (f16*)alloc((size_t)D * D * 2);
    f16* WvT = (f16*)alloc((size_t)D * D * 2);
    f16* WdT = (f16*)alloc((size_t)D * D * 2);
    float* scores = (float*)p;
    long long avail = (long long)ws_size - (long long)(p - (char*)d_ws);
    long long sbytes = (long long)S * S * 4;
    int g = (avail >= 4 * sbytes) ? 4 : (avail >= 2 * sbytes) ? 2 : 1;
    f16* att = xq;  // alias: xq is dead after the q projection

    dim3 blk(256);
    cvt_f16<<<dim3((unsigned)(TEN / 1024)), blk, 0, stream>>>(query, xq);
    cvt_f16<<<dim3((unsigned)(TEN / 1024)), blk, 0, stream>>>(keys, xk);
    cvt_f16<<<dim3((unsigned)(TEN / 1024)), blk, 0, stream>>>(values, xv);

    dim3 tgrid(D / 32, D / 32);
    wtrans<<<tgrid, blk, 0, stream>>>(Wq, WqT, D);
    wtrans<<<tgrid, blk, 0, stream>>>(Wk, WkT, D);
    wtrans<<<tgrid, blk, 0, stream>>>(Wv, WvT, D);
    wtrans<<<tgrid, blk, 0, stream>>>(Wd, WdT, D);

    dim3 pgrid(D / BN, (NB * S) / BM, 1);  // (8, 64)
    g_proj<<<pgrid, blk, 0, stream>>>(xq, D, WqT, D, q16, D, bq, D);
    g_proj<<<pgrid, blk, 0, stream>>>(xk, D, WkT, D, k16, D, bk, D);
    g_projT<<<pgrid, blk, 0, stream>>>(xv, D, WvT, D, vT, bv, D);

    for (int g0 = 0; g0 < NB; g0 += g) {
        int gz = (NB - g0 < g) ? (NB - g0) : g;
        dim3 sgrid(S / BN, S / BM, gz);  // (16,16,gz)
        g_scores<<<sgrid, blk, 0, stream>>>(
            q16 + (size_t)g0 * S * D, D, (long long)S * D,
            k16 + (size_t)g0 * S * D, D, (long long)S * D,
            scores, S, (long long)S * S, D);
        softmax_k<<<dim3((unsigned)(gz * S)), blk, 0, stream>>>(scores);
        dim3 agrid(D / BN, S / BM, gz);  // (8,16,gz)
        g_attnv<<<agrid, blk, 0, stream>>>(
            (const f16*)scores, 2 * S, (long long)S * 2 * S,
            vT + (size_t)g0 * D * S, S, (long long)D * S,
            att + (size_t)g0 * S * D, D, (long long)S * D, S);
    }

    g_out<<<pgrid, blk, 0, stream>>>(att, D, WdT, D, out, D, bd, D);
}

// Round 3
// 505.782 us; speedup vs baseline: 1.2772x; 1.0579x over previous
//
#include <hip/hip_runtime.h>
#include <stdint.h>

#define BM 128
#define BN 128
#define BK 64

typedef _Float16 f16;
typedef __attribute__((ext_vector_type(8))) _Float16 f16x8;
typedef __attribute__((ext_vector_type(4))) _Float16 f16x4;
typedef __attribute__((ext_vector_type(4))) float floatx4;

static __device__ __forceinline__ void async_load16(const void* g, void* l) {
    __builtin_amdgcn_global_load_lds(
        (const __attribute__((address_space(1))) unsigned int*)g,
        (__attribute__((address_space(3))) unsigned int*)l, 16, 0, 0);
}

// Stage a 128x64 f16 tile from global (row-major, ld elements) into LDS
// laid out as [8 kblk][128 m][8 k]. Chunk c (16B) <-> (kblk=c>>7, m=c&127).
static __device__ __forceinline__ void stage_tile(const f16* src, int ld, f16* lds, int tid) {
    int lane = tid & 63;
    int base = (tid >> 6) * 64;
#pragma unroll
    for (int t = 0; t < 4; ++t) {
        int c = base + t * 256 + lane;
        int m = c & 127, kb = c >> 7;
        const f16* gp = src + (size_t)m * ld + kb * 8;
        f16* lp = lds + (size_t)(base + t * 256) * 8;  // wave-uniform; HW adds lane*16B
        async_load16(gp, lp);
    }
}

static __device__ __forceinline__ f16x8 frag(const f16* lds, int row, int kblk) {
    return *(const f16x8*)(lds + ((kblk << 7) + row) * 8);
}

// CMODE: 0 = fp32 out (+bias), 1 = f16 out (+bias), 3 = f16 transposed vT out (+bias)
template <int CMODE>
static __device__ __forceinline__ void gemm_body(
    const f16* Ap, int lda, long long a_zoff,
    const f16* Bp, int ldb, long long b_zoff,
    void* Cp, int ldc, long long c_zoff,
    const float* bias, int K, int z)
{
    __shared__ __align__(16) f16 As[8 * 128 * 8];
    __shared__ __align__(16) f16 Bs[8 * 128 * 8];

    int tid = threadIdx.x;
    int lane = tid & 63;
    int wid = tid >> 6;
    int wm = wid >> 1, wn = wid & 1;
    size_t row0 = (size_t)blockIdx.y * BM;
    size_t col0 = (size_t)blockIdx.x * BN;

    floatx4 acc[4][4];
#pragma unroll
    for (int i = 0; i < 4; ++i)
#pragma unroll
        for (int j = 0; j < 4; ++j) acc[i][j] = floatx4{0.f, 0.f, 0.f, 0.f};

    const f16* a0 = Ap + (size_t)z * a_zoff + row0 * lda;
    const f16* b0 = Bp + (size_t)z * b_zoff + col0 * ldb;

    int quad = lane >> 4, mr = lane & 15;

    for (int k0 = 0; k0 < K; k0 += BK) {
        __syncthreads();
        stage_tile(a0 + k0, lda, As, tid);
        stage_tile(b0 + k0, ldb, Bs, tid);
        __syncthreads();

#pragma unroll
        for (int s = 0; s < 2; ++s) {
            f16x8 ah[4];
#pragma unroll
            for (int i = 0; i < 4; ++i) ah[i] = frag(As, wm * 64 + i * 16 + mr, s * 4 + quad);
#pragma unroll
            for (int j = 0; j < 4; ++j) {
                f16x8 bh = frag(Bs, wn * 64 + j * 16 + mr, s * 4 + quad);
#pragma unroll
                for (int i = 0; i < 4; ++i)
                    acc[i][j] = __builtin_amdgcn_mfma_f32_16x16x32_f16(ah[i], bh, acc[i][j], 0, 0, 0);
            }
        }
    }

#pragma unroll
    for (int i = 0; i < 4; ++i) {
#pragma unroll
        for (int j = 0; j < 4; ++j) {
#pragma unroll
            for (int r = 0; r < 4; ++r) {
                size_t rr = row0 + (size_t)(wm * 64 + i * 16 + quad * 4 + r);
                size_t cc = col0 + (size_t)(wn * 64 + j * 16 + mr);
                float v = acc[i][j][r];
                if (bias) v += bias[cc];
                if constexpr (CMODE == 0) {
                    float* C = (float*)Cp + (size_t)z * c_zoff;
                    C[rr * ldc + cc] = v;
                } else if constexpr (CMODE == 1) {
                    f16* C = (f16*)Cp + (size_t)z * c_zoff;
                    C[rr * ldc + cc] = (f16)v;
                } else {  // vT[b][col][s]: b = rr>>11, s = rr&2047, col dim 1024
                    f16* C = (f16*)Cp;
                    size_t b = rr >> 11, s = rr & 2047;
                    C[((b << 10) + cc) * 2048 + s] = (f16)v;
                }
            }
        }
    }
}

// Merged q/k/v projection: z selects input tensor, weight, bias, output mode.
// x = [xq|xk|xv] contiguous, W = [WqT|WkT|WvT] contiguous, qk = [q16|k16] contiguous.
__global__ __launch_bounds__(256, 2) void g_qkv(const f16* x, const f16* W,
                                                f16* qk, f16* vT,
                                                const float* bq, const float* bk,
                                                const float* bv, int D, long long ten) {
    int z = blockIdx.z;
    const float* bias = (z == 0) ? bq : (z == 1) ? bk : bv;
    if (z < 2) {
        gemm_body<1>(x + (size_t)z * ten, D, 0, W + (size_t)z * D * D, D, 0,
                     qk + (size_t)z * ten, D, 0, bias, D, 0);
    } else {
        gemm_body<3>(x + (size_t)2 * ten, D, 0, W + (size_t)2 * D * D, D, 0,
                     vT, 0, 0, bias, D, 0);
    }
}
__global__ __launch_bounds__(256, 2) void g_scores(const f16* A, int lda, long long az,
                                                   const f16* B, int ldb, long long bz,
                                                   float* C, int ldc, long long cz, int K) {
    gemm_body<0>(A, lda, az, B, ldb, bz, C, ldc, cz, nullptr, K, blockIdx.z);
}
__global__ __launch_bounds__(256, 2) void g_attnv(const f16* A, int lda, long long az,
                                                  const f16* B, int ldb, long long bz,
                                                  f16* C, int ldc, long long cz, int K) {
    gemm_body<1>(A, lda, az, B, ldb, bz, C, ldc, cz, nullptr, K, blockIdx.z);
}
__global__ __launch_bounds__(256, 2) void g_out(const f16* A, int lda, const f16* B, int ldb,
                                                float* C, int ldc, const float* bias, int K) {
    gemm_body<0>(A, lda, 0, B, ldb, 0, C, ldc, 0, bias, K, 0);
}

// fp32 -> fp16 convert for q/k/v in one dispatch; dst = [xq|xk|xv] contiguous.
__global__ __launch_bounds__(256) void cvt_f16(const float* q, const float* k, const float* v,
                                               f16* dst, long long ten) {
    int z = blockIdx.y;
    const float* src = (z == 0) ? q : (z == 1) ? k : v;
    size_t i = ((size_t)blockIdx.x * 256 + threadIdx.x) * 4;
    float4 x = *(const float4*)(src + i);
    f16x4 h = {(f16)x.x, (f16)x.y, (f16)x.z, (f16)x.w};
    *(f16x4*)(dst + (size_t)z * ten + i) = h;
}

// All four weight transposes in one dispatch; T = [WqT|WkT|WvT|WdT] contiguous.
__global__ __launch_bounds__(256) void wtrans(const float* Wq, const float* Wk,
                                              const float* Wv, const float* Wd,
                                              f16* T, int n) {
    __shared__ float tile[32][33];
    int z = blockIdx.z;
    const float* W = (z == 0) ? Wq : (z == 1) ? Wk : (z == 2) ? Wv : Wd;
    f16* Tz = T + (size_t)z * n * n;
    int bx = blockIdx.x * 32;
    int by = blockIdx.y * 32;
    int tx = threadIdx.x & 31;
    int ty = threadIdx.x >> 5;
    for (int r = ty; r < 32; r += 8) tile[r][tx] = W[(size_t)(by + r) * n + bx + tx];
    __syncthreads();
    for (int r = ty; r < 32; r += 8) Tz[(size_t)(bx + r) * n + by + tx] = (f16)tile[tx][r];
}

// One block per row of 2048 fp32 logits; writes fp16 attn into the first half
// of the same row's storage (row byte stride stays 8192 => f16 lda 4096).
__global__ __launch_bounds__(256) void softmax_k(float* scores) {
    size_t row = blockIdx.x;
    float* rp = scores + row * 2048;
    int tid = threadIdx.x;
    int lane = tid & 63, w = tid >> 6;
    float x[8];
    float mx = -3.4e38f;
#pragma unroll
    for (int i = 0; i < 8; ++i) {
        x[i] = rp[tid + i * 256];
        mx = fmaxf(mx, x[i]);
    }
#pragma unroll
    for (int o = 32; o > 0; o >>= 1) mx = fmaxf(mx, __shfl_xor(mx, o, 64));
    __shared__ float redm[4];
    __shared__ float reds[4];
    if (lane == 0) redm[w] = mx;
    __syncthreads();  // also orders: all row reads complete before any write below
    mx = fmaxf(fmaxf(redm[0], redm[1]), fmaxf(redm[2], redm[3]));
    float s = 0.f;
#pragma unroll
    for (int i = 0; i < 8; ++i) {
        x[i] = __expf(x[i] - mx);
        s += x[i];
    }
#pragma unroll
    for (int o = 32; o > 0; o >>= 1) s += __shfl_xor(s, o, 64);
    if (lane == 0) reds[w] = s;
    __syncthreads();
    s = reds[0] + reds[1] + reds[2] + reds[3];
    float inv = 1.f / s;
    f16* op = (f16*)rp;
#pragma unroll
    for (int i = 0; i < 8; ++i) op[tid + i * 256] = (f16)(x[i] * inv);
}

extern "C" void kernel_launch(void* const* d_in, const int* in_sizes, int n_in,
                              void* d_out, int out_size, void* d_ws, size_t ws_size,
                              hipStream_t stream) {
    const float* query  = (const float*)d_in[0];
    const float* keys   = (const float*)d_in[1];
    const float* values = (const float*)d_in[2];
    const float* Wq = (const float*)d_in[3];
    const float* bq = (const float*)d_in[4];
    const float* Wk = (const float*)d_in[5];
    const float* bk = (const float*)d_in[6];
    const float* Wv = (const float*)d_in[7];
    const float* bv = (const float*)d_in[8];
    const float* Wd = (const float*)d_in[9];
    const float* bd = (const float*)d_in[10];
    float* out = (float*)d_out;

    const int S = 2048, D = 1024, NB = 4;
    const size_t TEN = (size_t)NB * S * D;  // 8.39M, TEN*2 bytes is 256-aligned

    char* p = (char*)d_ws;
    auto alloc = [&](size_t bytes) {
        char* r = p;
        p += (bytes + 255) & ~(size_t)255;
        return r;
    };
    f16* x3  = (f16*)alloc(TEN * 2 * 3);   // [xq|xk|xv]
    f16* q16 = (f16*)alloc(TEN * 2 * 2);   // [q16|k16]
    f16* k16 = q16 + TEN;
    f16* vT  = (f16*)alloc(TEN * 2);
    f16* WT  = (f16*)alloc((size_t)D * D * 2 * 4);  // [WqT|WkT|WvT|WdT]
    float* scores = (float*)p;
    long long avail = (long long)ws_size - (long long)(p - (char*)d_ws);
    long long sbytes = (long long)S * S * 4;
    int g = (avail >= 4 * sbytes) ? 4 : (avail >= 2 * sbytes) ? 2 : 1;
    f16* att = x3;  // alias: x3 is dead after the qkv projections

    dim3 blk(256);
    cvt_f16<<<dim3((unsigned)(TEN / 1024), 3), blk, 0, stream>>>(query, keys, values, x3, TEN);
    wtrans<<<dim3(D / 32, D / 32, 4), blk, 0, stream>>>(Wq, Wk, Wv, Wd, WT, D);

    g_qkv<<<dim3(D / BN, (NB * S) / BM, 3), blk, 0, stream>>>(
        x3, WT, q16, vT, bq, bk, bv, D, (long long)TEN);

    for (int g0 = 0; g0 < NB; g0 += g) {
        int gz = (NB - g0 < g) ? (NB - g0) : g;
        dim3 sgrid(S / BN, S / BM, gz);  // (16,16,gz)
        g_scores<<<sgrid, blk, 0, stream>>>(
            q16 + (size_t)g0 * S * D, D, (long long)S * D,
            k16 + (size_t)g0 * S * D, D, (long long)S * D,
            scores, S, (long long)S * S, D);
        softmax_k<<<dim3((unsigned)(gz * S)), blk, 0, stream>>>(scores);
        dim3 agrid(D / BN, S / BM, gz);  // (8,16,gz)
        g_attnv<<<agrid, blk, 0, stream>>>(
            (const f16*)scores, 2 * S, (long long)S * 2 * S,
            vT + (size_t)g0 * D * S, S, (long long)D * S,
            att + (size_t)g0 * S * D, D, (long long)S * D, S);
    }

    g_out<<<dim3(D / BN, (NB * S) / BM, 1), blk, 0, stream>>>(att, D, WT + (size_t)3 * D * D, D,
                                                              out, D, bd, D);
}

// Round 4
// 499.711 us; speedup vs baseline: 1.2927x; 1.0121x over previous
//
#include <hip/hip_runtime.h>
#include <stdint.h>

#define BM 128
#define BN 128
#define BK 64
#define TILE_ELEMS (8 * 128 * 8)  // one 128x64 f16 tile in LDS

typedef _Float16 f16;
typedef __attribute__((ext_vector_type(8))) _Float16 f16x8;
typedef __attribute__((ext_vector_type(4))) _Float16 f16x4;
typedef __attribute__((ext_vector_type(4))) float floatx4;

static __device__ __forceinline__ void async_load16(const void* g, void* l) {
    __builtin_amdgcn_global_load_lds(
        (const __attribute__((address_space(1))) unsigned int*)g,
        (__attribute__((address_space(3))) unsigned int*)l, 16, 0, 0);
}

// Stage a 128x64 f16 tile from global (row-major, ld elements) into LDS
// laid out as [8 kblk][128 m][8 k]. Chunk c (16B) <-> (kblk=c>>7, m=c&127).
static __device__ __forceinline__ void stage_tile(const f16* src, int ld, f16* lds, int tid) {
    int lane = tid & 63;
    int base = (tid >> 6) * 64;
#pragma unroll
    for (int t = 0; t < 4; ++t) {
        int c = base + t * 256 + lane;
        int m = c & 127, kb = c >> 7;
        const f16* gp = src + (size_t)m * ld + kb * 8;
        f16* lp = lds + (size_t)(base + t * 256) * 8;  // wave-uniform; HW adds lane*16B
        async_load16(gp, lp);
    }
}

static __device__ __forceinline__ f16x8 frag(const f16* lds, int row, int kblk) {
    return *(const f16x8*)(lds + ((kblk << 7) + row) * 8);
}

// CMODE: 0 = fp32 out (+bias), 1 = f16 out (+bias), 3 = f16 transposed vT out (+bias)
// Shared memory is passed in so multiple instantiations in one kernel share it.
template <int CMODE>
static __device__ __forceinline__ void gemm_body(
    f16* As, f16* Bs,
    const f16* Ap, int lda, long long a_zoff,
    const f16* Bp, int ldb, long long b_zoff,
    void* Cp, int ldc, long long c_zoff,
    const float* bias, int K, int z)
{
    int tid = threadIdx.x;
    int lane = tid & 63;
    int wid = tid >> 6;
    int wm = wid >> 1, wn = wid & 1;
    size_t row0 = (size_t)blockIdx.y * BM;
    size_t col0 = (size_t)blockIdx.x * BN;

    floatx4 acc[4][4];
#pragma unroll
    for (int i = 0; i < 4; ++i)
#pragma unroll
        for (int j = 0; j < 4; ++j) acc[i][j] = floatx4{0.f, 0.f, 0.f, 0.f};

    const f16* a0 = Ap + (size_t)z * a_zoff + row0 * lda;
    const f16* b0 = Bp + (size_t)z * b_zoff + col0 * ldb;

    int quad = lane >> 4, mr = lane & 15;

    for (int k0 = 0; k0 < K; k0 += BK) {
        __syncthreads();
        stage_tile(a0 + k0, lda, As, tid);
        stage_tile(b0 + k0, ldb, Bs, tid);
        __syncthreads();

#pragma unroll
        for (int s = 0; s < 2; ++s) {
            f16x8 ah[4];
#pragma unroll
            for (int i = 0; i < 4; ++i) ah[i] = frag(As, wm * 64 + i * 16 + mr, s * 4 + quad);
#pragma unroll
            for (int j = 0; j < 4; ++j) {
                f16x8 bh = frag(Bs, wn * 64 + j * 16 + mr, s * 4 + quad);
#pragma unroll
                for (int i = 0; i < 4; ++i)
                    acc[i][j] = __builtin_amdgcn_mfma_f32_16x16x32_f16(ah[i], bh, acc[i][j], 0, 0, 0);
            }
        }
    }

#pragma unroll
    for (int i = 0; i < 4; ++i) {
#pragma unroll
        for (int j = 0; j < 4; ++j) {
#pragma unroll
            for (int r = 0; r < 4; ++r) {
                size_t rr = row0 + (size_t)(wm * 64 + i * 16 + quad * 4 + r);
                size_t cc = col0 + (size_t)(wn * 64 + j * 16 + mr);
                float v = acc[i][j][r];
                if (bias) v += bias[cc];
                if constexpr (CMODE == 0) {
                    float* C = (float*)Cp + (size_t)z * c_zoff;
                    C[rr * ldc + cc] = v;
                } else if constexpr (CMODE == 1) {
                    f16* C = (f16*)Cp + (size_t)z * c_zoff;
                    C[rr * ldc + cc] = (f16)v;
                } else {  // vT[b][col][s]: b = rr>>11, s = rr&2047, col dim 1024
                    f16* C = (f16*)Cp;
                    size_t b = rr >> 11, s = rr & 2047;
                    C[((b << 10) + cc) * 2048 + s] = (f16)v;
                }
            }
        }
    }
}

#define DECL_SMEM                                        \
    __shared__ __align__(16) f16 smem[2 * TILE_ELEMS];   \
    f16* As = smem;                                      \
    f16* Bs = smem + TILE_ELEMS;

// Merged q/k/v projection: z selects input tensor, weight, bias, output mode.
// x = [xq|xk|xv] contiguous, W = [WqT|WkT|WvT] contiguous, qk = [q16|k16] contiguous.
__global__ __launch_bounds__(256, 2) void g_qkv(const f16* x, const f16* W,
                                                f16* qk, f16* vT,
                                                const float* bq, const float* bk,
                                                const float* bv, int D, long long ten) {
    DECL_SMEM
    int z = blockIdx.z;
    const float* bias = (z == 0) ? bq : (z == 1) ? bk : bv;
    if (z < 2) {
        gemm_body<1>(As, Bs, x + (size_t)z * ten, D, 0, W + (size_t)z * D * D, D, 0,
                     qk + (size_t)z * ten, D, 0, bias, D, 0);
    } else {
        gemm_body<3>(As, Bs, x + (size_t)2 * ten, D, 0, W + (size_t)2 * D * D, D, 0,
                     vT, 0, 0, bias, D, 0);
    }
}
__global__ __launch_bounds__(256, 2) void g_scores(const f16* A, int lda, long long az,
                                                   const f16* B, int ldb, long long bz,
                                                   float* C, int ldc, long long cz, int K) {
    DECL_SMEM
    gemm_body<0>(As, Bs, A, lda, az, B, ldb, bz, C, ldc, cz, nullptr, K, blockIdx.z);
}
__global__ __launch_bounds__(256, 2) void g_attnv(const f16* A, int lda, long long az,
                                                  const f16* B, int ldb, long long bz,
                                                  f16* C, int ldc, long long cz, int K) {
    DECL_SMEM
    gemm_body<1>(As, Bs, A, lda, az, B, ldb, bz, C, ldc, cz, nullptr, K, blockIdx.z);
}
__global__ __launch_bounds__(256, 2) void g_out(const f16* A, int lda, const f16* B, int ldb,
                                                float* C, int ldc, const float* bias, int K) {
    DECL_SMEM
    gemm_body<0>(As, Bs, A, lda, 0, B, ldb, 0, C, ldc, 0, bias, K, 0);
}

// fp32 -> fp16 convert for q/k/v in one dispatch; dst = [xq|xk|xv] contiguous.
__global__ __launch_bounds__(256) void cvt_f16(const float* q, const float* k, const float* v,
                                               f16* dst, long long ten) {
    int z = blockIdx.y;
    const float* src = (z == 0) ? q : (z == 1) ? k : v;
    size_t i = ((size_t)blockIdx.x * 256 + threadIdx.x) * 4;
    float4 x = *(const float4*)(src + i);
    f16x4 h = {(f16)x.x, (f16)x.y, (f16)x.z, (f16)x.w};
    *(f16x4*)(dst + (size_t)z * ten + i) = h;
}

// All four weight transposes in one dispatch; T = [WqT|WkT|WvT|WdT] contiguous.
__global__ __launch_bounds__(256) void wtrans(const float* Wq, const float* Wk,
                                              const float* Wv, const float* Wd,
                                              f16* T, int n) {
    __shared__ float tile[32][33];
    int z = blockIdx.z;
    const float* W = (z == 0) ? Wq : (z == 1) ? Wk : (z == 2) ? Wv : Wd;
    f16* Tz = T + (size_t)z * n * n;
    int bx = blockIdx.x * 32;
    int by = blockIdx.y * 32;
    int tx = threadIdx.x & 31;
    int ty = threadIdx.x >> 5;
    for (int r = ty; r < 32; r += 8) tile[r][tx] = W[(size_t)(by + r) * n + bx + tx];
    __syncthreads();
    for (int r = ty; r < 32; r += 8) Tz[(size_t)(bx + r) * n + by + tx] = (f16)tile[tx][r];
}

// One block per row of 2048 fp32 logits; writes fp16 attn into the first half
// of the same row's storage (row byte stride stays 8192 => f16 lda 4096).
__global__ __launch_bounds__(256) void softmax_k(float* scores) {
    size_t row = blockIdx.x;
    float* rp = scores + row * 2048;
    int tid = threadIdx.x;
    int lane = tid & 63, w = tid >> 6;
    float x[8];
    float mx = -3.4e38f;
#pragma unroll
    for (int i = 0; i < 8; ++i) {
        x[i] = rp[tid + i * 256];
        mx = fmaxf(mx, x[i]);
    }
#pragma unroll
    for (int o = 32; o > 0; o >>= 1) mx = fmaxf(mx, __shfl_xor(mx, o, 64));
    __shared__ float redm[4];
    __shared__ float reds[4];
    if (lane == 0) redm[w] = mx;
    __syncthreads();  // also orders: all row reads complete before any write below
    mx = fmaxf(fmaxf(redm[0], redm[1]), fmaxf(redm[2], redm[3]));
    float s = 0.f;
#pragma unroll
    for (int i = 0; i < 8; ++i) {
        x[i] = __expf(x[i] - mx);
        s += x[i];
    }
#pragma unroll
    for (int o = 32; o > 0; o >>= 1) s += __shfl_xor(s, o, 64);
    if (lane == 0) reds[w] = s;
    __syncthreads();
    s = reds[0] + reds[1] + reds[2] + reds[3];
    float inv = 1.f / s;
    f16* op = (f16*)rp;
#pragma unroll
    for (int i = 0; i < 8; ++i) op[tid + i * 256] = (f16)(x[i] * inv);
}

extern "C" void kernel_launch(void* const* d_in, const int* in_sizes, int n_in,
                              void* d_out, int out_size, void* d_ws, size_t ws_size,
                              hipStream_t stream) {
    const float* query  = (const float*)d_in[0];
    const float* keys   = (const float*)d_in[1];
    const float* values = (const float*)d_in[2];
    const float* Wq = (const float*)d_in[3];
    const float* bq = (const float*)d_in[4];
    const float* Wk = (const float*)d_in[5];
    const float* bk = (const float*)d_in[6];
    const float* Wv = (const float*)d_in[7];
    const float* bv = (const float*)d_in[8];
    const float* Wd = (const float*)d_in[9];
    const float* bd = (const float*)d_in[10];
    float* out = (float*)d_out;

    const int S = 2048, D = 1024, NB = 4;
    const size_t TEN = (size_t)NB * S * D;  // 8.39M, TEN*2 bytes is 256-aligned

    char* p = (char*)d_ws;
    auto alloc = [&](size_t bytes) {
        char* r = p;
        p += (bytes + 255) & ~(size_t)255;
        return r;
    };
    f16* x3  = (f16*)alloc(TEN * 2 * 3);   // [xq|xk|xv]
    f16* q16 = (f16*)alloc(TEN * 2 * 2);   // [q16|k16]
    f16* k16 = q16 + TEN;
    f16* vT  = (f16*)alloc(TEN * 2);
    f16* WT  = (f16*)alloc((size_t)D * D * 2 * 4);  // [WqT|WkT|WvT|WdT]
    float* scores = (float*)p;
    long long avail = (long long)ws_size - (long long)(p - (char*)d_ws);
    long long sbytes = (long long)S * S * 4;
    int g = (avail >= 4 * sbytes) ? 4 : (avail >= 2 * sbytes) ? 2 : 1;
    f16* att = x3;  // alias: x3 is dead after the qkv projections

    dim3 blk(256);
    cvt_f16<<<dim3((unsigned)(TEN / 1024), 3), blk, 0, stream>>>(query, keys, values, x3, TEN);
    wtrans<<<dim3(D / 32, D / 32, 4), blk, 0, stream>>>(Wq, Wk, Wv, Wd, WT, D);

    g_qkv<<<dim3(D / BN, (NB * S) / BM, 3), blk, 0, stream>>>(
        x3, WT, q16, vT, bq, bk, bv, D, (long long)TEN);

    for (int g0 = 0; g0 < NB; g0 += g) {
        int gz = (NB - g0 < g) ? (NB - g0) : g;
        dim3 sgrid(S / BN, S / BM, gz);  // (16,16,gz)
        g_scores<<<sgrid, blk, 0, stream>>>(
            q16 + (size_t)g0 * S * D, D, (long long)S * D,
            k16 + (size_t)g0 * S * D, D, (long long)S * D,
            scores, S, (long long)S * S, D);
        softmax_k<<<dim3((unsigned)(gz * S)), blk, 0, stream>>>(scores);
        dim3 agrid(D / BN, S / BM, gz);  // (8,16,gz)
        g_attnv<<<agrid, blk, 0, stream>>>(
            (const f16*)scores, 2 * S, (long long)S * 2 * S,
            vT + (size_t)g0 * D * S, S, (long long)D * S,
            att + (size_t)g0 * S * D, D, (long long)S * D, S);
    }

    g_out<<<dim3(D / BN, (NB * S) / BM, 1), blk, 0, stream>>>(att, D, WT + (size_t)3 * D * D, D,
                                                              out, D, bd, D);
}